// Round 5
// baseline (24833.853 us; speedup 1.0000x reference)
//
#include <hip/hip_runtime.h>
#include <cstdint>

#define B_   32
#define T_   500
#define H_   512
#define ENC_ 1024
#define V_   10000
#define L_   100
#define H4_  2048
#define NB_  256
#define NT_  1024

// workspace layout (float offsets), total ~13.49M floats = 54 MB
#define OFF_HPROJ 0
#define OFF_WYYP  8192000    // packed Wyy bf16 hi/lo frags: 10.24M shorts
#define OFF_S     13312000
#define OFF_C0    13328384
#define OFF_C1    13344768
#define OFF_RACC  13361152   // 32 x 2048
#define OFF_DACC  13426688   // 32 x 512
#define OFF_G     13443072   // 32 x 1024
#define OFF_E     13475840   // 32 x 500
#define OFF_BAR   13492224   // barrier counters
#define INIT_CNT  180288

using bf16x8 = __attribute__((ext_vector_type(8))) short;
using f32x4  = __attribute__((ext_vector_type(4))) float;

__device__ __forceinline__ f32x4 mfma16(bf16x8 a, bf16x8 b, f32x4 c){
  return __builtin_amdgcn_mfma_f32_16x16x32_bf16(a, b, c, 0, 0, 0);
}
__device__ __forceinline__ unsigned short bfr(float f){
  unsigned x = __float_as_uint(f);
  return (unsigned short)((x + 0x7FFFu + ((x>>16)&1u)) >> 16);
}
__device__ __forceinline__ void bfsplit(float f, short& hi, short& lo){
  unsigned short h = bfr(f);
  float hf = __uint_as_float(((unsigned)h) << 16);
  hi = (short)h;
  lo = (short)bfr(f - hf);
}
__device__ __forceinline__ float ftanh(float x){
  float t = fminf(fmaxf(2.f*x, -30.f), 30.f);
  float e = __expf(t);
  return (e - 1.f) / (e + 1.f);
}
__device__ __forceinline__ float fsig(float x){
  float t = fminf(fmaxf(x, -30.f), 30.f);
  return 1.f / (1.f + __expf(-t));
}
// agent-scope relaxed atomics: coherent at L3, bypass stale L1/L2
__device__ __forceinline__ float gload(const float* p){
  return __hip_atomic_load((float*)p, __ATOMIC_RELAXED, __HIP_MEMORY_SCOPE_AGENT);
}
__device__ __forceinline__ void gstore(float* p, float v){
  __hip_atomic_store(p, v, __ATOMIC_RELAXED, __HIP_MEMORY_SCOPE_AGENT);
}
__device__ __forceinline__ void gload2(const float* p, float& a, float& b){
  unsigned long long u = __hip_atomic_load((const unsigned long long*)p,
                          __ATOMIC_RELAXED, __HIP_MEMORY_SCOPE_AGENT);
  a = __uint_as_float((unsigned)u);
  b = __uint_as_float((unsigned)(u >> 32));
}

// two-level grid barrier, monotonic counters, no cache flush
__device__ __forceinline__ void gridbar(unsigned* bars, unsigned it){
  asm volatile("s_waitcnt vmcnt(0) lgkmcnt(0)" ::: "memory");
  __syncthreads();
  if (threadIdx.x == 0){
    unsigned* gc = bars + 1 + (blockIdx.x & 15);
    unsigned old = __hip_atomic_fetch_add(gc, 1u, __ATOMIC_RELAXED, __HIP_MEMORY_SCOPE_AGENT);
    if (old == it*16u + 15u)
      __hip_atomic_fetch_add(bars, 1u, __ATOMIC_RELAXED, __HIP_MEMORY_SCOPE_AGENT);
    while (__hip_atomic_load(bars, __ATOMIC_RELAXED, __HIP_MEMORY_SCOPE_AGENT) < (it+1u)*16u)
      __builtin_amdgcn_s_sleep(2);
  }
  __syncthreads();
  asm volatile("" ::: "memory");
}

__global__ void k_init(float* __restrict__ ws){
  int i = blockIdx.x * 256 + threadIdx.x;
  if (i < INIT_CNT) ws[OFF_S + i] = 0.f;
}

// pack Wyy -> bf16 hi/lo fragment layout: idx = ((kc*625+nt)*2+hl)*512 + lane*8 + j
__global__ void k_packW(const float* __restrict__ Wyy, float* __restrict__ ws){
  unsigned short* wp = (unsigned short*)(ws + OFF_WYYP);
  int t = blockIdx.x * 256 + threadIdx.x;
  if (t >= 16*625*64) return;
  int kc = t / (625*64);
  int r  = t - kc*(625*64);
  int nt = r >> 6;
  int lane = r & 63;
  int v  = nt*16 + (lane & 15);
  int k0 = kc*32 + ((lane >> 4) << 3);
  bf16x8 H, Lo;
  #pragma unroll
  for (int j = 0; j < 8; ++j){
    short h, lo;
    bfsplit(Wyy[(size_t)(k0+j)*V_ + v], h, lo);
    H[j] = h; Lo[j] = lo;
  }
  size_t base = ((size_t)(kc*625 + nt)*2)*512 + (size_t)lane*8;
  *(bf16x8*)(wp + base) = H;
  *(bf16x8*)(wp + base + 512) = Lo;
}

// h_proj[m,n] = h_batch[m,:] @ Wh[:,n] + bias[n]
__global__ void k_hproj(const float* __restrict__ A, const float* __restrict__ W,
                        const float* __restrict__ bias, const int* __restrict__ lens,
                        float* __restrict__ C){
  const int bm = blockIdx.x * 64;
  const int bn = blockIdx.y * 64;
  {
    int b0 = bm / T_, t0 = bm % T_;
    int b1 = (bm + 63) / T_;
    if (b0 == b1 && t0 >= lens[b0]) return;
  }
  __shared__ float As[64][33];
  __shared__ float Bs[32][68];
  const int tid = threadIdx.x;
  const int tx = tid & 15, ty = tid >> 4;
  float acc[4][4];
  #pragma unroll
  for (int i = 0; i < 4; ++i)
    #pragma unroll
    for (int j = 0; j < 4; ++j) acc[i][j] = 0.f;
  for (int k0 = 0; k0 < 1024; k0 += 32){
    for (int i = tid; i < 64*32; i += 256){
      int rr = i >> 5, cc = i & 31;
      As[rr][cc] = A[(size_t)(bm + rr) * 1024 + k0 + cc];
    }
    for (int i = tid; i < 32*64; i += 256){
      int rr = i >> 6, cc = i & 63;
      Bs[rr][cc] = W[(size_t)(k0 + rr) * 512 + bn + cc];
    }
    __syncthreads();
    #pragma unroll
    for (int kk = 0; kk < 32; ++kk){
      float a0 = As[ty*4+0][kk], a1 = As[ty*4+1][kk];
      float a2 = As[ty*4+2][kk], a3 = As[ty*4+3][kk];
      float4 b4 = *(const float4*)&Bs[kk][tx*4];
      acc[0][0] += a0*b4.x; acc[0][1] += a0*b4.y; acc[0][2] += a0*b4.z; acc[0][3] += a0*b4.w;
      acc[1][0] += a1*b4.x; acc[1][1] += a1*b4.y; acc[1][2] += a1*b4.z; acc[1][3] += a1*b4.w;
      acc[2][0] += a2*b4.x; acc[2][1] += a2*b4.y; acc[2][2] += a2*b4.z; acc[2][3] += a2*b4.w;
      acc[3][0] += a3*b4.x; acc[3][1] += a3*b4.y; acc[3][2] += a3*b4.z; acc[3][3] += a3*b4.w;
    }
    __syncthreads();
  }
  #pragma unroll
  for (int i = 0; i < 4; ++i){
    int m = bm + ty*4 + i;
    float4 o;
    o.x = acc[i][0] + bias[bn + tx*4 + 0];
    o.y = acc[i][1] + bias[bn + tx*4 + 1];
    o.z = acc[i][2] + bias[bn + tx*4 + 2];
    o.w = acc[i][3] + bias[bn + tx*4 + 3];
    *(float4*)&C[(size_t)m * 512 + bn + tx*4] = o;
  }
}

__global__ __launch_bounds__(1024) void k_persist(
    const float* __restrict__ hb,  const int* __restrict__ lens,
    const int* __restrict__ labels,
    const float* __restrict__ Ws,  const float* __restrict__ av,
    const float* __restrict__ Wsy, const float* __restrict__ bsy,
    const float* __restrict__ Wgy, const float* __restrict__ bgy,
    const float* __restrict__ byy,
    const float* __restrict__ Eyr, const float* __restrict__ Wsr,
    const float* __restrict__ bsr, const float* __restrict__ Wgr,
    const float* __restrict__ bgr,
    float* __restrict__ out, float* __restrict__ ws)
{
  const int blk = blockIdx.x;
  const int tid = threadIdx.x;
  unsigned* bars = (unsigned*)(ws + OFF_BAR);
  const unsigned short* wyyp = (const unsigned short*)(ws + OFF_WYYP);
  __shared__ __align__(16) float smem[8704];   // 34.8 KB

  const int w    = tid >> 6;
  const int lane = tid & 63;

  for (int l = 0; l <= L_; ++l){
    // ================= P0 =================
    if (blk < 126){
      // vocab for step l-1: out[b,l-1,:] = tanh(dacc+bias) @ Wyy + byy  (MFMA)
      if (l > 0){
        const int ntg = blk >> 1, bt = blk & 1;
        const int nt0 = ntg * 10;
        const int ncnt = (625 - nt0 < 10) ? (625 - nt0) : 10;
        // A-frags (this wave's kc = w), built in registers from dacc
        const int ab = bt*16 + (lane & 15);
        const int k0 = w*32 + ((lane >> 4) << 3);
        bf16x8 Ahi, Alo;
        {
          float x[8];
          gload2(&ws[OFF_DACC + ab*H_ + k0 + 0], x[0], x[1]);
          gload2(&ws[OFF_DACC + ab*H_ + k0 + 2], x[2], x[3]);
          gload2(&ws[OFF_DACC + ab*H_ + k0 + 4], x[4], x[5]);
          gload2(&ws[OFF_DACC + ab*H_ + k0 + 6], x[6], x[7]);
          float4 b1 = *(const float4*)&bsy[k0];
          float4 b2 = *(const float4*)&bsy[k0+4];
          float4 b3 = *(const float4*)&bgy[k0];
          float4 b4 = *(const float4*)&bgy[k0+4];
          float bb[8] = {b1.x+b3.x, b1.y+b3.y, b1.z+b3.z, b1.w+b3.w,
                         b2.x+b4.x, b2.y+b4.y, b2.z+b4.z, b2.w+b4.w};
          #pragma unroll
          for (int j = 0; j < 8; ++j){
            short h, lo2;
            bfsplit(ftanh(x[j] + bb[j]), h, lo2);
            Ahi[j] = h; Alo[j] = lo2;
          }
        }
        f32x4 acc[10];
        #pragma unroll
        for (int n = 0; n < 10; ++n) acc[n] = (f32x4){0.f,0.f,0.f,0.f};
        const unsigned short* wp = wyyp + (size_t)(w*625 + nt0)*1024 + (size_t)lane*8;
        #pragma unroll
        for (int n = 0; n < 10; ++n){
          if (n < ncnt){
            bf16x8 Bhi = *(const bf16x8*)(wp + (size_t)n*1024);
            bf16x8 Blo = *(const bf16x8*)(wp + (size_t)n*1024 + 512);
            acc[n] = mfma16(Ahi, Bhi, acc[n]);
            acc[n] = mfma16(Alo, Bhi, acc[n]);
            acc[n] = mfma16(Ahi, Blo, acc[n]);
          }
        }
        // combine 16 kc-partials via LDS atomic adds
        float* cacc = smem;                         // 2560 f32
        for (int i = tid; i < 2560; i += NT_) cacc[i] = 0.f;
        __syncthreads();
        #pragma unroll
        for (int n = 0; n < 10; ++n){
          if (n < ncnt){
            #pragma unroll
            for (int r = 0; r < 4; ++r)
              atomicAdd(&cacc[n*256 + lane*4 + r], acc[n][r]);
          }
        }
        __syncthreads();
        const int lv = l - 1;
        for (int i = tid; i < ncnt*256; i += NT_){
          int n = i >> 8, rem = i & 255, ln = rem >> 2, r = rem & 3;
          int v  = (nt0 + n)*16 + (ln & 15);
          int bb = bt*16 + ((ln >> 4) << 2) + r;
          out[((size_t)bb*L_ + lv)*V_ + v] = cacc[i] + byy[v];
        }
      }
    } else if (blk < 254){
      // e-blocks: redundant LSTM -> s; sws = s@Ws; e rows
      if (l < L_){
        const int u = blk - 126, b = u >> 2, ch = u & 3;
        float* ssm  = smem;         // 512
        float* part = smem + 512;   // 1024
        float* wsm  = smem + 1536;  // 512
        if (l == 0){
          if (tid < 512) ssm[tid] = 0.f;
        } else {
          if (tid < 512){
            const int h = tid;
            const float* ey = Eyr + (size_t)labels[b*L_ + (l-1)] * H4_;
            float ri, rf, rg, ro;
            ri = gload(&ws[OFF_RACC + b*H4_ + h])        + bsr[h]        + bgr[h]        + ey[h];
            rf = gload(&ws[OFF_RACC + b*H4_ + 512 + h])  + bsr[512+h]    + bgr[512+h]    + ey[512+h];
            rg = gload(&ws[OFF_RACC + b*H4_ + 1024 + h]) + bsr[1024+h]   + bgr[1024+h]   + ey[1024+h];
            ro = gload(&ws[OFF_RACC + b*H4_ + 1536 + h]) + bsr[1536+h]   + bgr[1536+h]   + ey[1536+h];
            const int cro = OFF_C0 + (((l-1)&1) << 14);
            const int cwo = OFF_C0 + ((l&1) << 14);
            float cold = gload(&ws[cro + b*H_ + h]);
            float cn = fsig(rf)*cold + fsig(ri)*ftanh(rg);
            float sn = fsig(ro)*ftanh(cn);
            if (ch == 0){
              gstore(&ws[cwo + b*H_ + h], cn);
              gstore(&ws[OFF_S + b*H_ + h], sn);
            }
            ssm[h] = sn;
          }
        }
        __syncthreads();
        // sws partial: col = tid&511, k-half = tid>>9
        {
          const int col = tid & 511, kh = tid >> 9;
          const float* wp = Ws + (size_t)(kh*256)*H_ + col;
          const float* sp = ssm + kh*256;
          float acc = 0.f;
          float w0[8], w1[8];
          #pragma unroll
          for (int j = 0; j < 8; ++j) w0[j] = wp[(size_t)j * H_];
          for (int kk = 0; kk < 256; kk += 8){
            if (kk + 8 < 256){
              #pragma unroll
              for (int j = 0; j < 8; ++j) w1[j] = wp[(size_t)(kk+8+j) * H_];
            }
            #pragma unroll
            for (int j = 0; j < 8; ++j) acc += sp[kk+j] * w0[j];
            #pragma unroll
            for (int j = 0; j < 8; ++j) w0[j] = w1[j];
          }
          part[kh*512 + col] = acc;
        }
        __syncthreads();
        if (tid < 512) wsm[tid] = part[tid] + part[512 + tid];
        __syncthreads();
        // e rows
        const int len = lens[b];
        const int clen = (len + 3) >> 2;
        const int t0 = ch*clen, t1 = min(t0 + clen, len);
        float* e = ws + OFF_E;
        for (int t = t0 + w; t < t1; t += 16){
          const float* hp = ws + OFF_HPROJ + (size_t)(b*T_ + t) * H_;
          float sum = 0.f;
          #pragma unroll
          for (int it = 0; it < 2; ++it){
            int h = it*256 + lane*4;
            float4 a  = *(const float4*)&hp[h];
            float4 sw = *(const float4*)&wsm[h];
            float4 vv = *(const float4*)&av[h];
            sum += vv.x * ftanh(a.x + sw.x);
            sum += vv.y * ftanh(a.y + sw.y);
            sum += vv.z * ftanh(a.z + sw.z);
            sum += vv.w * ftanh(a.w + sw.w);
          }
          #pragma unroll
          for (int off = 32; off > 0; off >>= 1) sum += __shfl_xor(sum, off, 64);
          if (lane == 0) gstore(&e[b*T_ + t], sum);
        }
      }
    } else {
      // blocks 254,255: zero g for this step
      if (l < L_){
        int i = (blk - 254)*NT_ + tid;
        for (; i < B_*ENC_; i += 2*NT_) gstore(&ws[OFF_G + i], 0.f);
      }
    }
    if (l == L_) break;
    gridbar(bars, (unsigned)(l*3 + 0));

    // ================= P1: softmax + partial g (all 256 blocks) =================
    {
      const int b = blk >> 3, oct = blk & 7;
      const int len = lens[b];
      float* sc  = smem;        // 512
      float* red = smem + 512;  // 512
      float val = -1e30f;
      if (tid < 512){
        val = (tid < len) ? gload(&ws[OFF_E + b*T_ + tid]) : -1e30f;
        sc[tid]  = val;
        red[tid] = val;
      }
      __syncthreads();
      for (int st = 256; st > 0; st >>= 1){
        if (tid < st) red[tid] = fmaxf(red[tid], red[tid+st]);
        __syncthreads();
      }
      const float mx = red[0];
      __syncthreads();
      if (tid < 512){
        float ex = (tid < len) ? __expf(val - mx) : 0.f;
        sc[tid]  = ex;
        red[tid] = ex;
      }
      __syncthreads();
      for (int st = 256; st > 0; st >>= 1){
        if (tid < st) red[tid] += red[tid+st];
        __syncthreads();
      }
      const float inv = 1.f / red[0];
      const int clen = (len + 7) >> 3;
      const int t0 = oct*clen, t1 = min(t0 + clen, len);
      const float* hp = hb + (size_t)b*T_*ENC_ + tid;
      float acc = 0.f;
      #pragma unroll 4
      for (int t = t0; t < t1; ++t) acc += sc[t] * hp[(size_t)t * ENC_];
      if (t1 > t0) atomicAdd(&ws[OFF_G + b*ENC_ + tid], acc * inv);
    }
    gridbar(bars, (unsigned)(l*3 + 1));

    // ================= P2: dacc/racc = [s|g] @ Wcat  (MFMA, blk<160) =================
    if (blk < 160){
      const int nt = blk;
      unsigned short* bl = (unsigned short*)smem;   // 16 kc x 2 hl x 64 x 8 = 32 KB
      float* cacc = smem + 8192;                    // 512 f32
      f32x4 acc0 = (f32x4){0.f,0.f,0.f,0.f};
      f32x4 acc1 = (f32x4){0.f,0.f,0.f,0.f};
      for (int c = 0; c < 3; ++c){
        // build B chunk (16 kc) from fp32 weights
        {
          const int kcl = tid >> 6, ln = tid & 63;
          const int kc = c*16 + kcl;
          const int col = nt*16 + (ln & 15);
          const int kk0 = kc*32 + ((ln >> 4) << 3);
          bf16x8 H, Lo;
          #pragma unroll
          for (int j = 0; j < 8; ++j){
            int k = kk0 + j;
            float x;
            if (k < 512) x = (col < 512) ? Wsy[(size_t)k*512 + col]
                                         : Wsr[(size_t)k*2048 + (col-512)];
            else         x = (col < 512) ? Wgy[(size_t)(k-512)*512 + col]
                                         : Wgr[(size_t)(k-512)*2048 + (col-512)];
            short h, lo2;
            bfsplit(x, h, lo2);
            H[j] = h; Lo[j] = lo2;
          }
          *(bf16x8*)&bl[((kcl*2+0)*64 + ln)*8] = H;
          *(bf16x8*)&bl[((kcl*2+1)*64 + ln)*8] = Lo;
        }
        __syncthreads();
        // this wave's kc
        {
          const int kc = c*16 + w;
          const int kk0 = kc*32 + ((lane >> 4) << 3);
          bf16x8 Bhi = *(const bf16x8*)&bl[((w*2+0)*64 + lane)*8];
          bf16x8 Blo = *(const bf16x8*)&bl[((w*2+1)*64 + lane)*8];
          #pragma unroll
          for (int bt = 0; bt < 2; ++bt){
            const int ab = bt*16 + (lane & 15);
            float x[8];
            if (kk0 < 512){
              gload2(&ws[OFF_S + ab*H_ + kk0 + 0], x[0], x[1]);
              gload2(&ws[OFF_S + ab*H_ + kk0 + 2], x[2], x[3]);
              gload2(&ws[OFF_S + ab*H_ + kk0 + 4], x[4], x[5]);
              gload2(&ws[OFF_S + ab*H_ + kk0 + 6], x[6], x[7]);
            } else {
              const int kg = kk0 - 512;
              gload2(&ws[OFF_G + ab*ENC_ + kg + 0], x[0], x[1]);
              gload2(&ws[OFF_G + ab*ENC_ + kg + 2], x[2], x[3]);
              gload2(&ws[OFF_G + ab*ENC_ + kg + 4], x[4], x[5]);
              gload2(&ws[OFF_G + ab*ENC_ + kg + 6], x[6], x[7]);
            }
            bf16x8 Ahi, Alo;
            #pragma unroll
            for (int j = 0; j < 8; ++j){
              short h, lo2;
              bfsplit(x[j], h, lo2);
              Ahi[j] = h; Alo[j] = lo2;
            }
            if (bt == 0){
              acc0 = mfma16(Ahi, Bhi, acc0);
              acc0 = mfma16(Alo, Bhi, acc0);
              acc0 = mfma16(Ahi, Blo, acc0);
            } else {
              acc1 = mfma16(Ahi, Bhi, acc1);
              acc1 = mfma16(Alo, Bhi, acc1);
              acc1 = mfma16(Ahi, Blo, acc1);
            }
          }
        }
        __syncthreads();
      }
      if (tid < 512) cacc[tid] = 0.f;
      __syncthreads();
      #pragma unroll
      for (int r = 0; r < 4; ++r){
        atomicAdd(&cacc[lane*4 + r], acc0[r]);
        atomicAdd(&cacc[256 + lane*4 + r], acc1[r]);
      }
      __syncthreads();
      if (tid < 512){
        const int bt = tid >> 8, rem = tid & 255, ln = rem >> 2, r = rem & 3;
        const int bb = bt*16 + ((ln >> 4) << 2) + r;
        const int col = nt*16 + (ln & 15);
        const float vvv = cacc[bt*256 + ln*4 + r];
        if (col < 512) gstore(&ws[OFF_DACC + bb*H_ + col], vvv);
        else           gstore(&ws[OFF_RACC + bb*H4_ + (col-512)], vvv);
      }
    }
    gridbar(bars, (unsigned)(l*3 + 2));
  }
}

extern "C" void kernel_launch(void* const* d_in, const int* in_sizes, int n_in,
                              void* d_out, int out_size, void* d_ws, size_t ws_size,
                              hipStream_t stream){
  const float* h_batch = (const float*)d_in[0];
  const int*   seq_lens= (const int*)d_in[1];
  const int*   labels  = (const int*)d_in[2];
  const float* attn_Ws = (const float*)d_in[3];
  const float* attn_Wh = (const float*)d_in[4];
  const float* attn_b  = (const float*)d_in[5];
  const float* attn_v  = (const float*)d_in[6];
  const float* W_sy    = (const float*)d_in[7];
  const float* b_sy    = (const float*)d_in[8];
  const float* W_gy    = (const float*)d_in[9];
  const float* b_gy    = (const float*)d_in[10];
  const float* W_yy    = (const float*)d_in[11];
  const float* b_yy    = (const float*)d_in[12];
  const float* E_yr    = (const float*)d_in[13];
  const float* W_sr    = (const float*)d_in[14];
  const float* b_sr    = (const float*)d_in[15];
  const float* W_gr    = (const float*)d_in[16];
  const float* b_gr    = (const float*)d_in[17];
  float* out = (float*)d_out;
  float* ws  = (float*)d_ws;

  k_init <<<705, 256, 0, stream>>>(ws);
  k_packW<<<2500, 256, 0, stream>>>(W_yy, ws);
  k_hproj<<<dim3(250, 8), 256, 0, stream>>>(h_batch, attn_Wh, attn_b, seq_lens,
                                            ws + OFF_HPROJ);

  void* kargs[] = {
    (void*)&h_batch, (void*)&seq_lens, (void*)&labels,
    (void*)&attn_Ws, (void*)&attn_v,
    (void*)&W_sy, (void*)&b_sy, (void*)&W_gy, (void*)&b_gy,
    (void*)&b_yy,
    (void*)&E_yr, (void*)&W_sr, (void*)&b_sr, (void*)&W_gr, (void*)&b_gr,
    (void*)&out, (void*)&ws
  };
  hipLaunchCooperativeKernel((void*)k_persist, dim3(NB_), dim3(NT_), kargs, 0, stream);
}

// Round 7
// 14005.499 us; speedup vs baseline: 1.7732x; 1.7732x over previous
//
#include <hip/hip_runtime.h>
#include <cstdint>

#define B_   32
#define T_   500
#define H_   512
#define ENC_ 1024
#define V_   10000
#define L_   100
#define H4_  2048
#define NB_  256
#define NT_  512

// workspace layout (float offsets), total 13,492,288 floats = 54.0 MB (== round-5 size, known OK)
#define OFF_HPROJ 0          // bf16 [16000][512]  (2.048M floats used)
#define OFF_WYYP  4096000    // bf16 [625 vt][16 kc][2 hl][64][8] = 5.12M floats
#define OFF_WRECP 9216000    // bf16 [160 vt][48 kc][2 hl][64][8] = 3.932M floats
#define OFF_WSB   13148160   // bf16 [512 k][512 col] = 131072 floats
#define OFF_S     13279232
#define OFF_C0    13295616
#define OFF_C1    13312000   // (unused spare)
#define OFF_RACC  13328384   // 32 x 2048
#define OFF_DACC  13393920   // 32 x 512
#define OFF_G0    13410304   // 32 x 1024
#define OFF_G1    13443072   // 32 x 1024
#define OFF_E     13475840   // 32 x 500
#define OFF_BAR   13492224
#define ZERO_CNT  213056     // OFF_S .. OFF_BAR+64

using bf16x8 = __attribute__((ext_vector_type(8))) short;
using f32x4  = __attribute__((ext_vector_type(4))) float;

__device__ __forceinline__ f32x4 mfma16(bf16x8 a, bf16x8 b, f32x4 c){
  return __builtin_amdgcn_mfma_f32_16x16x32_bf16(a, b, c, 0, 0, 0);
}
__device__ __forceinline__ unsigned short bfr(float f){
  unsigned x = __float_as_uint(f);
  return (unsigned short)((x + 0x7FFFu + ((x>>16)&1u)) >> 16);
}
__device__ __forceinline__ void bfsplit(float f, short& hi, short& lo){
  unsigned short h = bfr(f);
  float hf = __uint_as_float(((unsigned)h) << 16);
  hi = (short)h;
  lo = (short)bfr(f - hf);
}
__device__ __forceinline__ float bf2f(unsigned short u){
  return __uint_as_float(((unsigned)u) << 16);
}
__device__ __forceinline__ float ftanh(float x){
  float t = fminf(fmaxf(2.f*x, -30.f), 30.f);
  float e = __expf(t);
  return (e - 1.f) / (e + 1.f);
}
__device__ __forceinline__ float fsig(float x){
  float t = fminf(fmaxf(x, -30.f), 30.f);
  return 1.f / (1.f + __expf(-t));
}
// agent-scope relaxed atomics: coherent at L3, bypass stale L1/L2
__device__ __forceinline__ float gload(const float* p){
  return __hip_atomic_load((float*)p, __ATOMIC_RELAXED, __HIP_MEMORY_SCOPE_AGENT);
}
__device__ __forceinline__ void gstore(float* p, float v){
  __hip_atomic_store(p, v, __ATOMIC_RELAXED, __HIP_MEMORY_SCOPE_AGENT);
}
__device__ __forceinline__ void gload2(const float* p, float& a, float& b){
  unsigned long long u = __hip_atomic_load((const unsigned long long*)p,
                          __ATOMIC_RELAXED, __HIP_MEMORY_SCOPE_AGENT);
  a = __uint_as_float((unsigned)u);
  b = __uint_as_float((unsigned)(u >> 32));
}

// two-level grid barrier (16 groups x 16 blocks), monotonic counters, no cache flush
__device__ __forceinline__ void gridbar(unsigned* bars, unsigned it){
  asm volatile("s_waitcnt vmcnt(0) lgkmcnt(0)" ::: "memory");
  __syncthreads();
  if (threadIdx.x == 0){
    unsigned* gc = bars + 1 + (blockIdx.x & 15);
    unsigned old = __hip_atomic_fetch_add(gc, 1u, __ATOMIC_RELAXED, __HIP_MEMORY_SCOPE_AGENT);
    if (old == it*16u + 15u)
      __hip_atomic_fetch_add(bars, 1u, __ATOMIC_RELAXED, __HIP_MEMORY_SCOPE_AGENT);
    while (__hip_atomic_load(bars, __ATOMIC_RELAXED, __HIP_MEMORY_SCOPE_AGENT) < (it+1u)*16u)
      __builtin_amdgcn_s_sleep(2);
  }
  __syncthreads();
  asm volatile("" ::: "memory");
}

__global__ void k_init(float* __restrict__ ws){
  int i = blockIdx.x * 256 + threadIdx.x;
  if (i < ZERO_CNT) ws[OFF_S + i] = 0.f;
}

// pack Wyy hi/lo frags: ((vt*16+kc)*2+hl)*512 + lane*8 + j
__global__ void k_packWyy(const float* __restrict__ Wyy, float* __restrict__ ws){
  unsigned short* wp = (unsigned short*)(ws + OFF_WYYP);
  int t = blockIdx.x * 256 + threadIdx.x;      // 640,000
  if (t >= 625*16*64) return;
  int vt = t / 1024;
  int rem = t - vt*1024;
  int kc = rem >> 6, lane = rem & 63;
  int v  = vt*16 + (lane & 15);
  int k0 = kc*32 + ((lane >> 4) << 3);
  bf16x8 H, Lo;
  #pragma unroll
  for (int j = 0; j < 8; ++j){
    short h, lo; bfsplit(Wyy[(size_t)(k0+j)*V_ + v], h, lo);
    H[j] = h; Lo[j] = lo;
  }
  size_t base = ((size_t)(vt*16 + kc)*2)*512 + (size_t)lane*8;
  *(bf16x8*)(wp + base) = H;
  *(bf16x8*)(wp + base + 512) = Lo;
}

// pack [Wsy|Wsr ; Wgy|Wgr] hi/lo frags
__global__ void k_packWrec(const float* __restrict__ Wsy, const float* __restrict__ Wgy,
                           const float* __restrict__ Wsr, const float* __restrict__ Wgr,
                           float* __restrict__ ws){
  unsigned short* wp = (unsigned short*)(ws + OFF_WRECP);
  int t = blockIdx.x * 256 + threadIdx.x;      // 491,520
  if (t >= 160*48*64) return;
  int vt = t / (48*64);
  int rem = t - vt*(48*64);
  int kc = rem >> 6, lane = rem & 63;
  int col = vt*16 + (lane & 15);
  int k0  = kc*32 + ((lane >> 4) << 3);
  bf16x8 H, Lo;
  #pragma unroll
  for (int j = 0; j < 8; ++j){
    int k = k0 + j;
    float x;
    if (k < 512) x = (col < 512) ? Wsy[(size_t)k*512 + col] : Wsr[(size_t)k*2048 + (col-512)];
    else         x = (col < 512) ? Wgy[(size_t)(k-512)*512 + col] : Wgr[(size_t)(k-512)*2048 + (col-512)];
    short h, lo; bfsplit(x, h, lo);
    H[j] = h; Lo[j] = lo;
  }
  size_t base = ((size_t)(vt*48 + kc)*2)*512 + (size_t)lane*8;
  *(bf16x8*)(wp + base) = H;
  *(bf16x8*)(wp + base + 512) = Lo;
}

// pack attn_Ws to bf16 [k][col]
__global__ void k_packWs(const float* __restrict__ Ws, float* __restrict__ ws){
  unsigned short* wp = (unsigned short*)(ws + OFF_WSB);
  int i = blockIdx.x * 256 + threadIdx.x;      // 262,144
  wp[i] = bfr(Ws[i]);
}

// h_proj = h_batch @ Wh + bias, stored bf16
__global__ void k_hproj(const float* __restrict__ A, const float* __restrict__ W,
                        const float* __restrict__ bias, const int* __restrict__ lens,
                        float* __restrict__ ws){
  unsigned short* C = (unsigned short*)(ws + OFF_HPROJ);
  const int bm = blockIdx.x * 64;
  const int bn = blockIdx.y * 64;
  {
    int b0 = bm / T_, t0 = bm % T_;
    int b1 = (bm + 63) / T_;
    if (b0 == b1 && t0 >= lens[b0]) return;
  }
  __shared__ float As[64][33];
  __shared__ float Bs[32][68];
  const int tid = threadIdx.x;
  const int tx = tid & 15, ty = tid >> 4;
  float acc[4][4];
  #pragma unroll
  for (int i = 0; i < 4; ++i)
    #pragma unroll
    for (int j = 0; j < 4; ++j) acc[i][j] = 0.f;
  for (int k0 = 0; k0 < 1024; k0 += 32){
    for (int i = tid; i < 64*32; i += 256){
      int rr = i >> 5, cc = i & 31;
      As[rr][cc] = A[(size_t)(bm + rr) * 1024 + k0 + cc];
    }
    for (int i = tid; i < 32*64; i += 256){
      int rr = i >> 6, cc = i & 63;
      Bs[rr][cc] = W[(size_t)(k0 + rr) * 512 + bn + cc];
    }
    __syncthreads();
    #pragma unroll
    for (int kk = 0; kk < 32; ++kk){
      float a0 = As[ty*4+0][kk], a1 = As[ty*4+1][kk];
      float a2 = As[ty*4+2][kk], a3 = As[ty*4+3][kk];
      float4 b4 = *(const float4*)&Bs[kk][tx*4];
      acc[0][0] += a0*b4.x; acc[0][1] += a0*b4.y; acc[0][2] += a0*b4.z; acc[0][3] += a0*b4.w;
      acc[1][0] += a1*b4.x; acc[1][1] += a1*b4.y; acc[1][2] += a1*b4.z; acc[1][3] += a1*b4.w;
      acc[2][0] += a2*b4.x; acc[2][1] += a2*b4.y; acc[2][2] += a2*b4.z; acc[2][3] += a2*b4.w;
      acc[3][0] += a3*b4.x; acc[3][1] += a3*b4.y; acc[3][2] += a3*b4.z; acc[3][3] += a3*b4.w;
    }
    __syncthreads();
  }
  #pragma unroll
  for (int i = 0; i < 4; ++i){
    int m = bm + ty*4 + i;
    ushort4 o;
    o.x = bfr(acc[i][0] + bias[bn + tx*4 + 0]);
    o.y = bfr(acc[i][1] + bias[bn + tx*4 + 1]);
    o.z = bfr(acc[i][2] + bias[bn + tx*4 + 2]);
    o.w = bfr(acc[i][3] + bias[bn + tx*4 + 3]);
    *(ushort4*)&C[(size_t)m * 512 + bn + tx*4] = o;
  }
}

__global__ __launch_bounds__(NT_, 2) void k_persist(
    const float* __restrict__ hb,  const int* __restrict__ lens,
    const int* __restrict__ labels, const float* __restrict__ av,
    const float* __restrict__ bsy, const float* __restrict__ bgy,
    const float* __restrict__ byy,
    const float* __restrict__ Eyr,
    const float* __restrict__ bsr, const float* __restrict__ bgr,
    float* __restrict__ out, float* __restrict__ ws)
{
  const int blk = blockIdx.x;
  const int tid = threadIdx.x;
  const int w   = tid >> 6;      // 0..7
  const int lane= tid & 63;
  unsigned* bars = (unsigned*)(ws + OFF_BAR);
  const unsigned short* wyyp  = (const unsigned short*)(ws + OFF_WYYP);
  const unsigned short* wrecp = (const unsigned short*)(ws + OFF_WRECP);
  const unsigned short* wsb   = (const unsigned short*)(ws + OFF_WSB);
  const unsigned short* hpB   = (const unsigned short*)(ws + OFF_HPROJ);
  __shared__ __align__(16) float smem[4096];   // 16 KB

  const int arow  = lane & 15;
  const int klane = (lane >> 4) << 3;

  for (int l = 0; l <= L_; ++l){
    const int p = l & 1;
    const int goff = p ? OFF_G1 : OFF_G0;
    // ========== P0: vocab(l-1) [blk 0..156]  ||  e(l) [blk 157..188] ==========
    if (blk < 157){
      if (l > 0){
        const int kh = w & 1;
        const int vtslot = w >> 1;           // 0..3
        const int vt = blk*4 + vtslot;
        f32x4 a0 = {0.f,0.f,0.f,0.f}, a1 = {0.f,0.f,0.f,0.f};
        if (vt < 625){
          for (int kc2 = 0; kc2 < 8; ++kc2){
            const int kc = kh*8 + kc2;
            const int k0 = kc*32 + klane;
            float bb[8];
            {
              float4 y1 = *(const float4*)&bsy[k0];
              float4 y2 = *(const float4*)&bsy[k0+4];
              float4 y3 = *(const float4*)&bgy[k0];
              float4 y4 = *(const float4*)&bgy[k0+4];
              bb[0]=y1.x+y3.x; bb[1]=y1.y+y3.y; bb[2]=y1.z+y3.z; bb[3]=y1.w+y3.w;
              bb[4]=y2.x+y4.x; bb[5]=y2.y+y4.y; bb[6]=y2.z+y4.z; bb[7]=y2.w+y4.w;
            }
            bf16x8 Ahi0, Alo0, Ahi1, Alo1;
            {
              float x[8];
              gload2(&ws[OFF_DACC + arow*H_ + k0 + 0], x[0], x[1]);
              gload2(&ws[OFF_DACC + arow*H_ + k0 + 2], x[2], x[3]);
              gload2(&ws[OFF_DACC + arow*H_ + k0 + 4], x[4], x[5]);
              gload2(&ws[OFF_DACC + arow*H_ + k0 + 6], x[6], x[7]);
              #pragma unroll
              for (int j = 0; j < 8; ++j){
                short h, lo; bfsplit(ftanh(x[j] + bb[j]), h, lo);
                Ahi0[j] = h; Alo0[j] = lo;
              }
            }
            {
              float x[8];
              gload2(&ws[OFF_DACC + (arow+16)*H_ + k0 + 0], x[0], x[1]);
              gload2(&ws[OFF_DACC + (arow+16)*H_ + k0 + 2], x[2], x[3]);
              gload2(&ws[OFF_DACC + (arow+16)*H_ + k0 + 4], x[4], x[5]);
              gload2(&ws[OFF_DACC + (arow+16)*H_ + k0 + 6], x[6], x[7]);
              #pragma unroll
              for (int j = 0; j < 8; ++j){
                short h, lo; bfsplit(ftanh(x[j] + bb[j]), h, lo);
                Ahi1[j] = h; Alo1[j] = lo;
              }
            }
            const unsigned short* wp = wyyp + ((size_t)(vt*16 + kc)*2)*512 + (size_t)lane*8;
            bf16x8 Bhi = *(const bf16x8*)wp;
            bf16x8 Blo = *(const bf16x8*)(wp + 512);
            a0 = mfma16(Ahi0, Bhi, a0);
            a0 = mfma16(Alo0, Bhi, a0);
            a0 = mfma16(Ahi0, Blo, a0);
            a1 = mfma16(Ahi1, Bhi, a1);
            a1 = mfma16(Alo1, Bhi, a1);
            a1 = mfma16(Ahi1, Blo, a1);
          }
        }
        if (vt < 625 && kh == 0){
          #pragma unroll
          for (int r = 0; r < 4; ++r){
            smem[vtslot*512 +       lane*4 + r] = a0[r];
            smem[vtslot*512 + 256 + lane*4 + r] = a1[r];
          }
        }
        __syncthreads();
        if (vt < 625 && kh == 1){
          const int v = vt*16 + arow;
          const float bv = byy[v];
          const int lv = l - 1;
          #pragma unroll
          for (int r = 0; r < 4; ++r){
            const int row0 = ((lane >> 4) << 2) + r;
            float v0 = smem[vtslot*512 +       lane*4 + r] + a0[r] + bv;
            float v1 = smem[vtslot*512 + 256 + lane*4 + r] + a1[r] + bv;
            out[((size_t)(row0)*L_      + lv)*V_ + v] = v0;
            out[((size_t)(row0 + 16)*L_ + lv)*V_ + v] = v1;
          }
        }
      }
    } else if (blk < 189){
      if (l < L_){
        const int b = blk - 157;
        float* ssm = smem;           // 512: s[b,:]
        float* part = smem + 512;    // 2048: sws partials
        float* wsm = smem + 2560;    // 512: sws[b,:]
        // redundant LSTM(l-1) for this b (this block is the sole owner of b)
        if (l == 0){
          ssm[tid] = 0.f;
        } else {
          const int h = tid;
          const float* ey = Eyr + (size_t)labels[b*L_ + (l-1)] * H4_;
          float ri = gload(&ws[OFF_RACC + b*H4_ + h])        + bsr[h]      + bgr[h]      + ey[h];
          float rf = gload(&ws[OFF_RACC + b*H4_ + 512 + h])  + bsr[512+h]  + bgr[512+h]  + ey[512+h];
          float rg = gload(&ws[OFF_RACC + b*H4_ + 1024 + h]) + bsr[1024+h] + bgr[1024+h] + ey[1024+h];
          float ro = gload(&ws[OFF_RACC + b*H4_ + 1536 + h]) + bsr[1536+h] + bgr[1536+h] + ey[1536+h];
          float cold = gload(&ws[OFF_C0 + b*H_ + h]);
          float cn = fsig(rf)*cold + fsig(ri)*ftanh(rg);
          float sn = fsig(ro)*ftanh(cn);
          gstore(&ws[OFF_C0 + b*H_ + h], cn);
          gstore(&ws[OFF_S + b*H_ + h], sn);
          ssm[h] = sn;
        }
        __syncthreads();
        // sws[b,:] = s @ Ws  (bf16 Ws, split K in halves across thread groups)
        {
          const int colp = tid & 255;
          const int kh2  = tid >> 8;
          const int col0 = colp*2;
          const float* sp = ssm + kh2*256;
          const unsigned short* wb = wsb + (size_t)(kh2*256)*512 + col0;
          float acc0 = 0.f, acc1 = 0.f;
          for (int k = 0; k < 256; k += 8){
            float4 s0 = *(const float4*)&sp[k];
            float4 s1 = *(const float4*)&sp[k+4];
            unsigned wv[8];
            #pragma unroll
            for (int j = 0; j < 8; ++j)
              wv[j] = *(const unsigned*)&wb[(size_t)(k+j)*512];
            float sv[8] = {s0.x,s0.y,s0.z,s0.w,s1.x,s1.y,s1.z,s1.w};
            #pragma unroll
            for (int j = 0; j < 8; ++j){
              acc0 += sv[j] * bf2f((unsigned short)(wv[j] & 0xFFFFu));
              acc1 += sv[j] * bf2f((unsigned short)(wv[j] >> 16));
            }
          }
          part[kh2*1024 + col0]     = acc0;
          part[kh2*1024 + col0 + 1] = acc1;
        }
        __syncthreads();
        wsm[tid] = part[tid] + part[1024 + tid];
        __syncthreads();
        // e rows for this b (8 waves stride)
        const int len = lens[b];
        float avr[8], swr[8];
        #pragma unroll
        for (int j = 0; j < 8; ++j){
          avr[j] = av[lane*8 + j];
          swr[j] = wsm[lane*8 + j];
        }
        float* e = ws + OFF_E;
        for (int t = w; t < len; t += 8){
          bf16x8 hp = *(const bf16x8*)&hpB[(size_t)(b*T_ + t)*512 + lane*8];
          float sum = 0.f;
          #pragma unroll
          for (int j = 0; j < 8; ++j)
            sum += avr[j] * ftanh(bf2f((unsigned short)hp[j]) + swr[j]);
          #pragma unroll
          for (int off = 32; off > 0; off >>= 1) sum += __shfl_xor(sum, off, 64);
          if (lane == 0) gstore(&e[b*T_ + t], sum);
        }
      }
    }
    if (l == L_) break;     // uniform exit across all blocks
    gridbar(bars, (unsigned)(l*3 + 0));

    // ========== P1: softmax + partial g (all 256 blocks) ==========
    {
      const int b = blk >> 3, ts = blk & 7;
      const int len = lens[b];
      float* sc  = smem;          // 512
      float* red = smem + 512;    // 256
      float val = (tid < len) ? gload(&ws[OFF_E + b*T_ + tid]) : -1e30f;
      sc[tid] = val;
      __syncthreads();
      if (tid < 256) red[tid] = fmaxf(sc[tid], sc[tid+256]);
      __syncthreads();
      for (int st = 128; st > 0; st >>= 1){
        if (tid < st) red[tid] = fmaxf(red[tid], red[tid+st]);
        __syncthreads();
      }
      const float mx = red[0];
      __syncthreads();
      float ex = (tid < len) ? __expf(val - mx) : 0.f;
      sc[tid] = ex;
      __syncthreads();
      if (tid < 256) red[tid] = sc[tid] + sc[tid+256];
      __syncthreads();
      for (int st = 128; st > 0; st >>= 1){
        if (tid < st) red[tid] += red[tid+st];
        __syncthreads();
      }
      const float inv = 1.f / red[0];
      const int clen = (len + 7) >> 3;
      const int t0 = ts*clen, t1 = min(t0 + clen, len);
      const int col0 = tid*2;
      const float* hp = hb + (size_t)b*T_*ENC_ + col0;
      float ax = 0.f, ay = 0.f;
      for (int t = t0; t < t1; ++t){
        float2 x = *(const float2*)&hp[(size_t)t * ENC_];
        float a = sc[t];
        ax += a*x.x; ay += a*x.y;
      }
      if (t1 > t0){
        float* gp = ws + goff + b*ENC_ + col0;
        atomicAdd(gp+0, ax*inv);
        atomicAdd(gp+1, ay*inv);
      }
    }
    gridbar(bars, (unsigned)(l*3 + 1));

    // ========== P2: [dacc|racc] = [s|g] @ Wrec (MFMA, blk<80) ; zero g-parity ==========
    if (blk < 80){
      const int sub = w >> 2;          // 0..1 half-block
      const int w4  = w & 3;
      const int vt  = blk*2 + sub;     // 0..159
      f32x4 acc0 = {0.f,0.f,0.f,0.f}, acc1 = {0.f,0.f,0.f,0.f};
      for (int c = 0; c < 3; ++c){
        #pragma unroll
        for (int kc2 = 0; kc2 < 4; ++kc2){
          const int kc = c*16 + w4*4 + kc2;
          const int k0 = kc*32 + klane;
          bf16x8 Ahi0, Alo0, Ahi1, Alo1;
          {
            const float* src = (k0 < 512) ? &ws[OFF_S + arow*H_ + k0]
                                          : &ws[goff + arow*ENC_ + (k0 - 512)];
            float x[8];
            gload2(src+0, x[0], x[1]);
            gload2(src+2, x[2], x[3]);
            gload2(src+4, x[4], x[5]);
            gload2(src+6, x[6], x[7]);
            #pragma unroll
            for (int j = 0; j < 8; ++j){
              short h, lo; bfsplit(x[j], h, lo);
              Ahi0[j] = h; Alo0[j] = lo;
            }
          }
          {
            const float* src = (k0 < 512) ? &ws[OFF_S + (arow+16)*H_ + k0]
                                          : &ws[goff + (arow+16)*ENC_ + (k0 - 512)];
            float x[8];
            gload2(src+0, x[0], x[1]);
            gload2(src+2, x[2], x[3]);
            gload2(src+4, x[4], x[5]);
            gload2(src+6, x[6], x[7]);
            #pragma unroll
            for (int j = 0; j < 8; ++j){
              short h, lo; bfsplit(x[j], h, lo);
              Ahi1[j] = h; Alo1[j] = lo;
            }
          }
          const unsigned short* wp = wrecp + ((size_t)(vt*48 + kc)*2)*512 + (size_t)lane*8;
          bf16x8 Bhi = *(const bf16x8*)wp;
          bf16x8 Blo = *(const bf16x8*)(wp + 512);
          acc0 = mfma16(Ahi0, Bhi, acc0);
          acc0 = mfma16(Alo0, Bhi, acc0);
          acc0 = mfma16(Ahi0, Blo, acc0);
          acc1 = mfma16(Ahi1, Bhi, acc1);
          acc1 = mfma16(Alo1, Bhi, acc1);
          acc1 = mfma16(Ahi1, Blo, acc1);
        }
      }
      #pragma unroll
      for (int r = 0; r < 4; ++r){
        smem[sub*2048 + w4*512 +       lane*4 + r] = acc0[r];
        smem[sub*2048 + w4*512 + 256 + lane*4 + r] = acc1[r];
      }
      __syncthreads();
      #pragma unroll
      for (int oo = 0; oo < 2; ++oo){
        const int q   = tid + oo*512;
        const int sb  = q >> 9;
        const int rem = q & 511;
        const int bt  = rem >> 8;
        const int r8  = rem & 255;
        const int ln  = r8 >> 2, rr = r8 & 3;
        float v = smem[sb*2048 +        bt*256 + r8] + smem[sb*2048 +  512 + bt*256 + r8]
                + smem[sb*2048 + 1024 + bt*256 + r8] + smem[sb*2048 + 1536 + bt*256 + r8];
        const int row = bt*16 + ((ln >> 4) << 2) + rr;
        const int col = (blk*2 + sb)*16 + (ln & 15);
        if (col < 512) gstore(&ws[OFF_DACC + row*H_ + col], v);
        else           gstore(&ws[OFF_RACC + row*H4_ + (col - 512)], v);
      }
    } else if (blk < 96){
      const int zoff = p ? OFF_G0 : OFF_G1;   // zero the other parity for next step
      int i = (blk - 80)*NT_ + tid;
      for (; i < B_*ENC_; i += 16*NT_) gstore(&ws[zoff + i], 0.f);
    }
    gridbar(bars, (unsigned)(l*3 + 2));
  }
}

extern "C" void kernel_launch(void* const* d_in, const int* in_sizes, int n_in,
                              void* d_out, int out_size, void* d_ws, size_t ws_size,
                              hipStream_t stream){
  const float* h_batch = (const float*)d_in[0];
  const int*   seq_lens= (const int*)d_in[1];
  const int*   labels  = (const int*)d_in[2];
  const float* attn_Ws = (const float*)d_in[3];
  const float* attn_Wh = (const float*)d_in[4];
  const float* attn_b  = (const float*)d_in[5];
  const float* attn_v  = (const float*)d_in[6];
  const float* W_sy    = (const float*)d_in[7];
  const float* b_sy    = (const float*)d_in[8];
  const float* W_gy    = (const float*)d_in[9];
  const float* b_gy    = (const float*)d_in[10];
  const float* W_yy    = (const float*)d_in[11];
  const float* b_yy    = (const float*)d_in[12];
  const float* E_yr    = (const float*)d_in[13];
  const float* W_sr    = (const float*)d_in[14];
  const float* b_sr    = (const float*)d_in[15];
  const float* W_gr    = (const float*)d_in[16];
  const float* b_gr    = (const float*)d_in[17];
  float* out = (float*)d_out;
  float* ws  = (float*)d_ws;

  k_init    <<<833, 256, 0, stream>>>(ws);
  k_packWyy <<<2500, 256, 0, stream>>>(W_yy, ws);
  k_packWrec<<<1920, 256, 0, stream>>>(W_sy, W_gy, W_sr, W_gr, ws);
  k_packWs  <<<1024, 256, 0, stream>>>(attn_Ws, ws);
  k_hproj   <<<dim3(250, 8), 256, 0, stream>>>(h_batch, attn_Wh, attn_b, seq_lens, ws);

  void* kargs[] = {
    (void*)&h_batch, (void*)&seq_lens, (void*)&labels, (void*)&attn_v,
    (void*)&b_sy, (void*)&b_gy, (void*)&b_yy,
    (void*)&E_yr, (void*)&b_sr, (void*)&b_gr,
    (void*)&out, (void*)&ws
  };
  hipLaunchCooperativeKernel((void*)k_persist, dim3(NB_), dim3(NT_), kargs, 0, stream);
}

// Round 8
// 10823.067 us; speedup vs baseline: 2.2945x; 1.2940x over previous
//
#include <hip/hip_runtime.h>
#include <cstdint>

#define B_   32
#define T_   500
#define H_   512
#define ENC_ 1024
#define V_   10000
#define L_   100
#define H4_  2048
#define NB_  256
#define NT_  512

// workspace layout (float offsets) — identical to round 7 (known good)
#define OFF_HPROJ 0          // bf16 [16000][512]
#define OFF_WYYP  4096000    // bf16 [625 vt][16 kc][2 hl][64][8]
#define OFF_WRECP 9216000    // bf16 [160 vt][48 kc][2 hl][64][8]
#define OFF_WSB   13148160   // bf16 [512 k][512 col]
#define OFF_S     13279232
#define OFF_C0    13295616   // unused (c lives in registers now)
#define OFF_C1    13312000
#define OFF_RACC  13328384   // 32 x 2048
#define OFF_DACC  13393920   // 32 x 512
#define OFF_G0    13410304   // 32 x 1024
#define OFF_G1    13443072   // 32 x 1024
#define OFF_E     13475840   // 32 x 500
#define OFF_BAR   13492224
#define ZERO_CNT  213056

using bf16x8 = __attribute__((ext_vector_type(8))) short;
using f32x4  = __attribute__((ext_vector_type(4))) float;

__device__ __forceinline__ f32x4 mfma16(bf16x8 a, bf16x8 b, f32x4 c){
  return __builtin_amdgcn_mfma_f32_16x16x32_bf16(a, b, c, 0, 0, 0);
}
__device__ __forceinline__ unsigned short bfr(float f){
  unsigned x = __float_as_uint(f);
  return (unsigned short)((x + 0x7FFFu + ((x>>16)&1u)) >> 16);
}
__device__ __forceinline__ void bfsplit(float f, short& hi, short& lo){
  unsigned short h = bfr(f);
  float hf = __uint_as_float(((unsigned)h) << 16);
  hi = (short)h;
  lo = (short)bfr(f - hf);
}
__device__ __forceinline__ float bf2f(unsigned short u){
  return __uint_as_float(((unsigned)u) << 16);
}
__device__ __forceinline__ float ftanh(float x){
  float t = fminf(fmaxf(2.f*x, -30.f), 30.f);
  float e = __expf(t);
  return (e - 1.f) / (e + 1.f);
}
__device__ __forceinline__ float fsig(float x){
  float t = fminf(fmaxf(x, -30.f), 30.f);
  return 1.f / (1.f + __expf(-t));
}
__device__ __forceinline__ float gload(const float* p){
  return __hip_atomic_load((float*)p, __ATOMIC_RELAXED, __HIP_MEMORY_SCOPE_AGENT);
}
__device__ __forceinline__ void gstore(float* p, float v){
  __hip_atomic_store(p, v, __ATOMIC_RELAXED, __HIP_MEMORY_SCOPE_AGENT);
}
__device__ __forceinline__ void gload2(const float* p, float& a, float& b){
  unsigned long long u = __hip_atomic_load((const unsigned long long*)p,
                          __ATOMIC_RELAXED, __HIP_MEMORY_SCOPE_AGENT);
  a = __uint_as_float((unsigned)u);
  b = __uint_as_float((unsigned)(u >> 32));
}

// two-level grid barrier (16 groups x 16 blocks), monotonic counters, no cache flush
__device__ __forceinline__ void gridbar(unsigned* bars, unsigned it){
  asm volatile("s_waitcnt vmcnt(0) lgkmcnt(0)" ::: "memory");
  __syncthreads();
  if (threadIdx.x == 0){
    unsigned* gc = bars + 1 + (blockIdx.x & 15);
    unsigned old = __hip_atomic_fetch_add(gc, 1u, __ATOMIC_RELAXED, __HIP_MEMORY_SCOPE_AGENT);
    if (old == it*16u + 15u)
      __hip_atomic_fetch_add(bars, 1u, __ATOMIC_RELAXED, __HIP_MEMORY_SCOPE_AGENT);
    while (__hip_atomic_load(bars, __ATOMIC_RELAXED, __HIP_MEMORY_SCOPE_AGENT) < (it+1u)*16u)
      __builtin_amdgcn_s_sleep(2);
  }
  __syncthreads();
  asm volatile("" ::: "memory");
}

__global__ void k_init(float* __restrict__ ws){
  int i = blockIdx.x * 256 + threadIdx.x;
  if (i < ZERO_CNT) ws[OFF_S + i] = 0.f;
}

__global__ void k_packWyy(const float* __restrict__ Wyy, float* __restrict__ ws){
  unsigned short* wp = (unsigned short*)(ws + OFF_WYYP);
  int t = blockIdx.x * 256 + threadIdx.x;
  if (t >= 625*16*64) return;
  int vt = t / 1024;
  int rem = t - vt*1024;
  int kc = rem >> 6, lane = rem & 63;
  int v  = vt*16 + (lane & 15);
  int k0 = kc*32 + ((lane >> 4) << 3);
  bf16x8 H, Lo;
  #pragma unroll
  for (int j = 0; j < 8; ++j){
    short h, lo; bfsplit(Wyy[(size_t)(k0+j)*V_ + v], h, lo);
    H[j] = h; Lo[j] = lo;
  }
  size_t base = ((size_t)(vt*16 + kc)*2)*512 + (size_t)lane*8;
  *(bf16x8*)(wp + base) = H;
  *(bf16x8*)(wp + base + 512) = Lo;
}

__global__ void k_packWrec(const float* __restrict__ Wsy, const float* __restrict__ Wgy,
                           const float* __restrict__ Wsr, const float* __restrict__ Wgr,
                           float* __restrict__ ws){
  unsigned short* wp = (unsigned short*)(ws + OFF_WRECP);
  int t = blockIdx.x * 256 + threadIdx.x;
  if (t >= 160*48*64) return;
  int vt = t / (48*64);
  int rem = t - vt*(48*64);
  int kc = rem >> 6, lane = rem & 63;
  int col = vt*16 + (lane & 15);
  int k0  = kc*32 + ((lane >> 4) << 3);
  bf16x8 H, Lo;
  #pragma unroll
  for (int j = 0; j < 8; ++j){
    int k = k0 + j;
    float x;
    if (k < 512) x = (col < 512) ? Wsy[(size_t)k*512 + col] : Wsr[(size_t)k*2048 + (col-512)];
    else         x = (col < 512) ? Wgy[(size_t)(k-512)*512 + col] : Wgr[(size_t)(k-512)*2048 + (col-512)];
    short h, lo; bfsplit(x, h, lo);
    H[j] = h; Lo[j] = lo;
  }
  size_t base = ((size_t)(vt*48 + kc)*2)*512 + (size_t)lane*8;
  *(bf16x8*)(wp + base) = H;
  *(bf16x8*)(wp + base + 512) = Lo;
}

__global__ void k_packWs(const float* __restrict__ Ws, float* __restrict__ ws){
  unsigned short* wp = (unsigned short*)(ws + OFF_WSB);
  int i = blockIdx.x * 256 + threadIdx.x;
  wp[i] = bfr(Ws[i]);
}

__global__ void k_hproj(const float* __restrict__ A, const float* __restrict__ W,
                        const float* __restrict__ bias, const int* __restrict__ lens,
                        float* __restrict__ ws){
  unsigned short* C = (unsigned short*)(ws + OFF_HPROJ);
  const int bm = blockIdx.x * 64;
  const int bn = blockIdx.y * 64;
  {
    int b0 = bm / T_, t0 = bm % T_;
    int b1 = (bm + 63) / T_;
    if (b0 == b1 && t0 >= lens[b0]) return;
  }
  __shared__ float As[64][33];
  __shared__ float Bs[32][68];
  const int tid = threadIdx.x;
  const int tx = tid & 15, ty = tid >> 4;
  float acc[4][4];
  #pragma unroll
  for (int i = 0; i < 4; ++i)
    #pragma unroll
    for (int j = 0; j < 4; ++j) acc[i][j] = 0.f;
  for (int k0 = 0; k0 < 1024; k0 += 32){
    for (int i = tid; i < 64*32; i += 256){
      int rr = i >> 5, cc = i & 31;
      As[rr][cc] = A[(size_t)(bm + rr) * 1024 + k0 + cc];
    }
    for (int i = tid; i < 32*64; i += 256){
      int rr = i >> 6, cc = i & 63;
      Bs[rr][cc] = W[(size_t)(k0 + rr) * 512 + bn + cc];
    }
    __syncthreads();
    #pragma unroll
    for (int kk = 0; kk < 32; ++kk){
      float a0 = As[ty*4+0][kk], a1 = As[ty*4+1][kk];
      float a2 = As[ty*4+2][kk], a3 = As[ty*4+3][kk];
      float4 b4 = *(const float4*)&Bs[kk][tx*4];
      acc[0][0] += a0*b4.x; acc[0][1] += a0*b4.y; acc[0][2] += a0*b4.z; acc[0][3] += a0*b4.w;
      acc[1][0] += a1*b4.x; acc[1][1] += a1*b4.y; acc[1][2] += a1*b4.z; acc[1][3] += a1*b4.w;
      acc[2][0] += a2*b4.x; acc[2][1] += a2*b4.y; acc[2][2] += a2*b4.z; acc[2][3] += a2*b4.w;
      acc[3][0] += a3*b4.x; acc[3][1] += a3*b4.y; acc[3][2] += a3*b4.z; acc[3][3] += a3*b4.w;
    }
    __syncthreads();
  }
  #pragma unroll
  for (int i = 0; i < 4; ++i){
    int m = bm + ty*4 + i;
    ushort4 o;
    o.x = bfr(acc[i][0] + bias[bn + tx*4 + 0]);
    o.y = bfr(acc[i][1] + bias[bn + tx*4 + 1]);
    o.z = bfr(acc[i][2] + bias[bn + tx*4 + 2]);
    o.w = bfr(acc[i][3] + bias[bn + tx*4 + 3]);
    *(ushort4*)&C[(size_t)m * 512 + bn + tx*4] = o;
  }
}

__global__ __launch_bounds__(NT_, 2) void k_persist(
    const float* __restrict__ hb,  const int* __restrict__ lens,
    const int* __restrict__ labels, const float* __restrict__ av,
    const float* __restrict__ bsy, const float* __restrict__ bgy,
    const float* __restrict__ byy,
    const float* __restrict__ Eyr,
    const float* __restrict__ bsr, const float* __restrict__ bgr,
    float* __restrict__ out, float* __restrict__ ws)
{
  const int blk = blockIdx.x;
  const int tid = threadIdx.x;
  const int w   = tid >> 6;
  const int lane= tid & 63;
  unsigned* bars = (unsigned*)(ws + OFF_BAR);
  const unsigned short* wyyp  = (const unsigned short*)(ws + OFF_WYYP);
  const unsigned short* wrecp = (const unsigned short*)(ws + OFF_WRECP);
  const unsigned short* wsb   = (const unsigned short*)(ws + OFF_WSB);
  const unsigned short* hpB   = (const unsigned short*)(ws + OFF_HPROJ);
  __shared__ __align__(16) float smem[4096];   // 16 KB

  const int arow  = lane & 15;
  const int klane = (lane >> 4) << 3;
  float c_reg = 0.f;                 // LSTM cell state, owned by state blocks

  for (int l = 0; l <= L_; ++l){
    const int p = l & 1;
    const int goff = p ? OFF_G1 : OFF_G0;
    // ===== A: vocab(l-1) [0..156] || state {LSTM,sws,e-half} [157..220] || zero g[p] [221..255]
    if (blk < 157){
      if (l > 0){
        const int kh = w & 1;
        const int vtslot = w >> 1;
        const int vt = blk*4 + vtslot;
        f32x4 a0 = {0.f,0.f,0.f,0.f}, a1 = {0.f,0.f,0.f,0.f};
        if (vt < 625){
          for (int kc2 = 0; kc2 < 8; ++kc2){
            const int kc = kh*8 + kc2;
            const int k0 = kc*32 + klane;
            float bb[8];
            {
              float4 y1 = *(const float4*)&bsy[k0];
              float4 y2 = *(const float4*)&bsy[k0+4];
              float4 y3 = *(const float4*)&bgy[k0];
              float4 y4 = *(const float4*)&bgy[k0+4];
              bb[0]=y1.x+y3.x; bb[1]=y1.y+y3.y; bb[2]=y1.z+y3.z; bb[3]=y1.w+y3.w;
              bb[4]=y2.x+y4.x; bb[5]=y2.y+y4.y; bb[6]=y2.z+y4.z; bb[7]=y2.w+y4.w;
            }
            bf16x8 Ahi0, Alo0, Ahi1, Alo1;
            {
              float x[8];
              gload2(&ws[OFF_DACC + arow*H_ + k0 + 0], x[0], x[1]);
              gload2(&ws[OFF_DACC + arow*H_ + k0 + 2], x[2], x[3]);
              gload2(&ws[OFF_DACC + arow*H_ + k0 + 4], x[4], x[5]);
              gload2(&ws[OFF_DACC + arow*H_ + k0 + 6], x[6], x[7]);
              #pragma unroll
              for (int j = 0; j < 8; ++j){
                short h, lo; bfsplit(ftanh(x[j] + bb[j]), h, lo);
                Ahi0[j] = h; Alo0[j] = lo;
              }
            }
            {
              float x[8];
              gload2(&ws[OFF_DACC + (arow+16)*H_ + k0 + 0], x[0], x[1]);
              gload2(&ws[OFF_DACC + (arow+16)*H_ + k0 + 2], x[2], x[3]);
              gload2(&ws[OFF_DACC + (arow+16)*H_ + k0 + 4], x[4], x[5]);
              gload2(&ws[OFF_DACC + (arow+16)*H_ + k0 + 6], x[6], x[7]);
              #pragma unroll
              for (int j = 0; j < 8; ++j){
                short h, lo; bfsplit(ftanh(x[j] + bb[j]), h, lo);
                Ahi1[j] = h; Alo1[j] = lo;
              }
            }
            const unsigned short* wp = wyyp + ((size_t)(vt*16 + kc)*2)*512 + (size_t)lane*8;
            bf16x8 Bhi = *(const bf16x8*)wp;
            bf16x8 Blo = *(const bf16x8*)(wp + 512);
            a0 = mfma16(Ahi0, Bhi, a0);
            a0 = mfma16(Alo0, Bhi, a0);
            a0 = mfma16(Ahi0, Blo, a0);
            a1 = mfma16(Ahi1, Bhi, a1);
            a1 = mfma16(Alo1, Bhi, a1);
            a1 = mfma16(Ahi1, Blo, a1);
          }
        }
        if (vt < 625 && kh == 0){
          #pragma unroll
          for (int r = 0; r < 4; ++r){
            smem[vtslot*512 +       lane*4 + r] = a0[r];
            smem[vtslot*512 + 256 + lane*4 + r] = a1[r];
          }
        }
        __syncthreads();
        if (vt < 625 && kh == 1){
          const int v = vt*16 + arow;
          const float bv = byy[v];
          const int lv = l - 1;
          #pragma unroll
          for (int r = 0; r < 4; ++r){
            const int row0 = ((lane >> 4) << 2) + r;
            float v0 = smem[vtslot*512 +       lane*4 + r] + a0[r] + bv;
            float v1 = smem[vtslot*512 + 256 + lane*4 + r] + a1[r] + bv;
            out[((size_t)(row0)*L_      + lv)*V_ + v] = v0;
            out[((size_t)(row0 + 16)*L_ + lv)*V_ + v] = v1;
          }
        }
        __syncthreads();
      }
    } else if (blk < 221){
      if (l < L_){
        const int u = blk - 157;
        const int b = u >> 1, half = u & 1;
        float* ssm = smem;           // 512: s[b,:]
        float* part = smem + 512;    // 2048: sws partials
        float* wsm = smem + 2560;    // 512: sws[b,:]
        // LSTM(l-1) for this b (both halves redundantly; identical fp ops -> identical results)
        if (l == 0){
          ssm[tid] = 0.f;
          c_reg = 0.f;
        } else {
          const int h = tid;
          const float* ey = Eyr + (size_t)labels[b*L_ + (l-1)] * H4_;
          float ri = gload(&ws[OFF_RACC + b*H4_ + h])        + bsr[h]      + bgr[h]      + ey[h];
          float rf = gload(&ws[OFF_RACC + b*H4_ + 512 + h])  + bsr[512+h]  + bgr[512+h]  + ey[512+h];
          float rg = gload(&ws[OFF_RACC + b*H4_ + 1024 + h]) + bsr[1024+h] + bgr[1024+h] + ey[1024+h];
          float ro = gload(&ws[OFF_RACC + b*H4_ + 1536 + h]) + bsr[1536+h] + bgr[1536+h] + ey[1536+h];
          float cn = fsig(rf)*c_reg + fsig(ri)*ftanh(rg);
          float sn = fsig(ro)*ftanh(cn);
          c_reg = cn;
          if (half == 0) gstore(&ws[OFF_S + b*H_ + h], sn);
          ssm[h] = sn;
        }
        __syncthreads();
        // sws[b,:] = s @ Ws  (bf16 Ws, L2-resident)
        {
          const int colp = tid & 255;
          const int kh2  = tid >> 8;
          const int col0 = colp*2;
          const float* sp = ssm + kh2*256;
          const unsigned short* wb = wsb + (size_t)(kh2*256)*512 + col0;
          float acc0 = 0.f, acc1 = 0.f;
          for (int k = 0; k < 256; k += 8){
            float4 s0 = *(const float4*)&sp[k];
            float4 s1 = *(const float4*)&sp[k+4];
            unsigned wv[8];
            #pragma unroll
            for (int j = 0; j < 8; ++j)
              wv[j] = *(const unsigned*)&wb[(size_t)(k+j)*512];
            float sv[8] = {s0.x,s0.y,s0.z,s0.w,s1.x,s1.y,s1.z,s1.w};
            #pragma unroll
            for (int j = 0; j < 8; ++j){
              acc0 += sv[j] * bf2f((unsigned short)(wv[j] & 0xFFFFu));
              acc1 += sv[j] * bf2f((unsigned short)(wv[j] >> 16));
            }
          }
          part[kh2*1024 + col0]     = acc0;
          part[kh2*1024 + col0 + 1] = acc1;
        }
        __syncthreads();
        wsm[tid] = part[tid] + part[1024 + tid];
        __syncthreads();
        // e rows: this half handles t = 2*w+half + 16*i
        const int len = lens[b];
        float avr[8], swr[8];
        #pragma unroll
        for (int j = 0; j < 8; ++j){
          avr[j] = av[lane*8 + j];
          swr[j] = wsm[lane*8 + j];
        }
        float* e = ws + OFF_E;
        for (int t = 2*w + half; t < len; t += 16){
          bf16x8 hp = *(const bf16x8*)&hpB[(size_t)(b*T_ + t)*512 + lane*8];
          float sum = 0.f;
          #pragma unroll
          for (int j = 0; j < 8; ++j)
            sum += avr[j] * ftanh(bf2f((unsigned short)hp[j]) + swr[j]);
          #pragma unroll
          for (int off = 32; off > 0; off >>= 1) sum += __shfl_xor(sum, off, 64);
          if (lane == 0) gstore(&e[b*T_ + t], sum);
        }
      }
    } else {
      if (l < L_){
        // zero g[p] for this step's accumulation
        for (int i = (blk - 221)*NT_ + tid; i < B_*ENC_; i += 35*NT_)
          gstore(&ws[goff + i], 0.f);
      }
    }
    if (l == L_) break;     // uniform exit
    gridbar(bars, (unsigned)(l*3 + 0));

    // ===== B: redundant softmax from e + wide parallel g-scan (all 256 blocks) =====
    {
      const int b = blk >> 3, ts = blk & 7;
      const int len = lens[b];
      float* sc  = smem;          // 512
      float* red = smem + 512;    // 256
      float* pg  = smem + 1024;   // 2048 partial-g combine
      float val = (tid < len) ? gload(&ws[OFF_E + b*T_ + tid]) : -1e30f;
      sc[tid] = val;
      __syncthreads();
      if (tid < 256) red[tid] = fmaxf(sc[tid], sc[tid+256]);
      __syncthreads();
      for (int st = 128; st > 0; st >>= 1){
        if (tid < st) red[tid] = fmaxf(red[tid], red[tid+st]);
        __syncthreads();
      }
      const float mx = red[0];
      __syncthreads();
      float ex = (tid < len) ? __expf(val - mx) : 0.f;
      sc[tid] = ex;
      __syncthreads();
      if (tid < 256) red[tid] = sc[tid] + sc[tid+256];
      __syncthreads();
      for (int st = 128; st > 0; st >>= 1){
        if (tid < st) red[tid] += red[tid+st];
        __syncthreads();
      }
      const float inv = 1.f / red[0];
      // scan: thread owns 4 cols; t interleaved 16-way (8 blocks x 2 thread-groups)
      const int tg  = tid >> 8;        // 0..1
      const int cq  = tid & 255;       // col quad
      const int col = cq * 4;
      const float* hp = hb + (size_t)b*T_*ENC_ + col;
      float4 acc = {0.f,0.f,0.f,0.f};
      for (int t = ts*2 + tg; t < len; t += 16){
        float4 x = *(const float4*)&hp[(size_t)t * ENC_];
        float a = sc[t];
        acc.x += a*x.x; acc.y += a*x.y; acc.z += a*x.z; acc.w += a*x.w;
      }
      *(float4*)&pg[tg*1024 + col] = acc;
      __syncthreads();
      if (tid < 256){
        float4 x0 = *(const float4*)&pg[col];
        float4 x1 = *(const float4*)&pg[1024 + col];
        float* gp = ws + goff + b*ENC_ + col;
        atomicAdd(gp+0, (x0.x+x1.x)*inv);
        atomicAdd(gp+1, (x0.y+x1.y)*inv);
        atomicAdd(gp+2, (x0.z+x1.z)*inv);
        atomicAdd(gp+3, (x0.w+x1.w)*inv);
      }
    }
    gridbar(bars, (unsigned)(l*3 + 1));

    // ===== C: [dacc|racc] = [s|g] @ Wrec (MFMA, blk<80) =====
    if (blk < 80){
      const int sub = w >> 2;
      const int w4  = w & 3;
      const int vt  = blk*2 + sub;
      f32x4 acc0 = {0.f,0.f,0.f,0.f}, acc1 = {0.f,0.f,0.f,0.f};
      for (int c = 0; c < 3; ++c){
        #pragma unroll
        for (int kc2 = 0; kc2 < 4; ++kc2){
          const int kc = c*16 + w4*4 + kc2;
          const int k0 = kc*32 + klane;
          bf16x8 Ahi0, Alo0, Ahi1, Alo1;
          {
            const float* src = (k0 < 512) ? &ws[OFF_S + arow*H_ + k0]
                                          : &ws[goff + arow*ENC_ + (k0 - 512)];
            float x[8];
            gload2(src+0, x[0], x[1]);
            gload2(src+2, x[2], x[3]);
            gload2(src+4, x[4], x[5]);
            gload2(src+6, x[6], x[7]);
            #pragma unroll
            for (int j = 0; j < 8; ++j){
              short h, lo; bfsplit(x[j], h, lo);
              Ahi0[j] = h; Alo0[j] = lo;
            }
          }
          {
            const float* src = (k0 < 512) ? &ws[OFF_S + (arow+16)*H_ + k0]
                                          : &ws[goff + (arow+16)*ENC_ + (k0 - 512)];
            float x[8];
            gload2(src+0, x[0], x[1]);
            gload2(src+2, x[2], x[3]);
            gload2(src+4, x[4], x[5]);
            gload2(src+6, x[6], x[7]);
            #pragma unroll
            for (int j = 0; j < 8; ++j){
              short h, lo; bfsplit(x[j], h, lo);
              Ahi1[j] = h; Alo1[j] = lo;
            }
          }
          const unsigned short* wp = wrecp + ((size_t)(vt*48 + kc)*2)*512 + (size_t)lane*8;
          bf16x8 Bhi = *(const bf16x8*)wp;
          bf16x8 Blo = *(const bf16x8*)(wp + 512);
          acc0 = mfma16(Ahi0, Bhi, acc0);
          acc0 = mfma16(Alo0, Bhi, acc0);
          acc0 = mfma16(Ahi0, Blo, acc0);
          acc1 = mfma16(Ahi1, Bhi, acc1);
          acc1 = mfma16(Alo1, Bhi, acc1);
          acc1 = mfma16(Ahi1, Blo, acc1);
        }
      }
      #pragma unroll
      for (int r = 0; r < 4; ++r){
        smem[sub*2048 + w4*512 +       lane*4 + r] = acc0[r];
        smem[sub*2048 + w4*512 + 256 + lane*4 + r] = acc1[r];
      }
      __syncthreads();
      #pragma unroll
      for (int oo = 0; oo < 2; ++oo){
        const int q   = tid + oo*512;
        const int sb  = q >> 9;
        const int rem = q & 511;
        const int bt  = rem >> 8;
        const int r8  = rem & 255;
        const int ln  = r8 >> 2, rr = r8 & 3;
        float v = smem[sb*2048 +        bt*256 + r8] + smem[sb*2048 +  512 + bt*256 + r8]
                + smem[sb*2048 + 1024 + bt*256 + r8] + smem[sb*2048 + 1536 + bt*256 + r8];
        const int row = bt*16 + ((ln >> 4) << 2) + rr;
        const int col = (blk*2 + sb)*16 + (ln & 15);
        if (col < 512) gstore(&ws[OFF_DACC + row*H_ + col], v);
        else           gstore(&ws[OFF_RACC + row*H4_ + (col - 512)], v);
      }
    }
    gridbar(bars, (unsigned)(l*3 + 2));
  }
}

extern "C" void kernel_launch(void* const* d_in, const int* in_sizes, int n_in,
                              void* d_out, int out_size, void* d_ws, size_t ws_size,
                              hipStream_t stream){
  const float* h_batch = (const float*)d_in[0];
  const int*   seq_lens= (const int*)d_in[1];
  const int*   labels  = (const int*)d_in[2];
  const float* attn_Ws = (const float*)d_in[3];
  const float* attn_Wh = (const float*)d_in[4];
  const float* attn_b  = (const float*)d_in[5];
  const float* attn_v  = (const float*)d_in[6];
  const float* W_sy    = (const float*)d_in[7];
  const float* b_sy    = (const float*)d_in[8];
  const float* W_gy    = (const float*)d_in[9];
  const float* b_gy    = (const float*)d_in[10];
  const float* W_yy    = (const float*)d_in[11];
  const float* b_yy    = (const float*)d_in[12];
  const float* E_yr    = (const float*)d_in[13];
  const float* W_sr    = (const float*)d_in[14];
  const float* b_sr    = (const float*)d_in[15];
  const float* W_gr    = (const float*)d_in[16];
  const float* b_gr    = (const float*)d_in[17];
  float* out = (float*)d_out;
  float* ws  = (float*)d_ws;

  k_init    <<<833, 256, 0, stream>>>(ws);
  k_packWyy <<<2500, 256, 0, stream>>>(W_yy, ws);
  k_packWrec<<<1920, 256, 0, stream>>>(W_sy, W_gy, W_sr, W_gr, ws);
  k_packWs  <<<1024, 256, 0, stream>>>(attn_Ws, ws);
  k_hproj   <<<dim3(250, 8), 256, 0, stream>>>(h_batch, attn_Wh, attn_b, seq_lens, ws);

  void* kargs[] = {
    (void*)&h_batch, (void*)&seq_lens, (void*)&labels, (void*)&attn_v,
    (void*)&b_sy, (void*)&b_gy, (void*)&b_yy,
    (void*)&E_yr, (void*)&b_sr, (void*)&b_gr,
    (void*)&out, (void*)&ws
  };
  hipLaunchCooperativeKernel((void*)k_persist, dim3(NB_), dim3(NT_), kargs, 0, stream);
}